// Round 9
// baseline (333.492 us; speedup 1.0000x reference)
//
#include <hip/hip_runtime.h>

#define NN 40000
#define DD 128
#define EE 640000

// ---------------- init: cnt = 0, zero BN sums ----------------
__global__ __launch_bounds__(256) void k_init(int* __restrict__ cnt,
                                              float* __restrict__ sums) {
    int i = blockIdx.x * 256 + threadIdx.x;
    if (i < NN) cnt[i] = 0;
    if (i < 256) sums[i] = 0.0f;   // 128 sum + 128 sumsq
}

// ---------------- rank[e] = cnt[col]++  (the ONLY atomic pass) ----------------
__global__ __launch_bounds__(256) void k_rank(const int* __restrict__ ei,
                                              int* __restrict__ cnt,
                                              int* __restrict__ rank) {
    int e = blockIdx.x * 256 + threadIdx.x;   // E = 2500*256 exactly
    int c = ei[EE + e];
    rank[e] = atomicAdd(&cnt[c], 1);
}

// ---------------- exclusive scan of cnt -> off (single block) ----------------
#define SCAN_CH 40
__global__ __launch_bounds__(1024) void k_scan(const int* __restrict__ cnt,
                                               int* __restrict__ off) {
    __shared__ int sm[1024];
    int t = threadIdx.x;
    int base = t * SCAN_CH;                   // 1000 threads cover 40000 exactly
    int s = 0;
    if (base < NN) {
#pragma unroll
        for (int i = 0; i < SCAN_CH; ++i) s += cnt[base + i];
    }
    sm[t] = s;
    __syncthreads();
    for (int d = 1; d < 1024; d <<= 1) {      // Hillis-Steele inclusive scan
        int v = (t >= d) ? sm[t - d] : 0;
        __syncthreads();
        sm[t] += v;
        __syncthreads();
    }
    if (base < NN) {
        int run = sm[t] - s;                  // exclusive base for this chunk
#pragma unroll
        for (int i = 0; i < SCAN_CH; ++i) {
            off[base + i] = run;
            run += cnt[base + i];
        }
    }
    if (t == 1023) off[NN] = sm[1023];        // == EE
}

// ---------------- permute edges into dest-sorted order (NO atomics) ----------------
__global__ __launch_bounds__(256) void k_permute(const int* __restrict__ ei,
                                                 const float* __restrict__ ew,
                                                 const int* __restrict__ rank,
                                                 const int* __restrict__ off,
                                                 int2* __restrict__ srn) {
    int e = blockIdx.x * 256 + threadIdx.x;   // 2500 blocks
    int r = ei[e], c = ei[EE + e];
    int pos = off[c] + rank[e];
    srn[pos] = make_int2(r, __float_as_int(ew[e]));
}

// ---------------- deg from CSR segments: dis = rsqrt(1 + sum ew), wave/node ----------------
__global__ __launch_bounds__(256) void k_degdis(const int* __restrict__ off,
                                                const int2* __restrict__ srn,
                                                float* __restrict__ dis) {
    int gid = blockIdx.x * 256 + threadIdx.x; // 10000 blocks -> 40000 waves
    int node = gid >> 6;
    int lane = gid & 63;
    int s = off[node], e = off[node + 1];
    float v = 0.0f;
    for (int p = s + lane; p < e; p += 64) v += __int_as_float(srn[p].y);
#pragma unroll
    for (int m = 1; m < 64; m <<= 1) v += __shfl_xor(v, m);
    if (lane == 0) dis[node] = rsqrtf(1.0f + v);
}

// ---------------- gather: one wave per node, norm computed on the fly ----------------
// 4-wide edge unroll: 4 independent x-row loads in flight per iter.
__global__ __launch_bounds__(256) void k_gather(const int* __restrict__ off,
                                                const int2* __restrict__ srn,
                                                const float* __restrict__ x,
                                                const float* __restrict__ dis,
                                                float* __restrict__ agg) {
    int gid = blockIdx.x * 256 + threadIdx.x; // 10000 blocks -> 40000 waves
    int node = gid >> 6;
    int lane = gid & 63;
    const float2* x2 = (const float2*)x;
    float dc = dis[node];
    float2 sv = x2[(size_t)node * 64 + lane];
    float2 acc0 = {sv.x * dc, sv.y * dc};     // self term: dc*(dc*x_c) after final scale
    float2 acc1 = {0.f, 0.f}, acc2 = {0.f, 0.f}, acc3 = {0.f, 0.f};
    int s = off[node], e_end = off[node + 1];
    for (int bse = s; bse < e_end; bse += 64) {
        int ee = bse + lane;
        bool act = (ee < e_end);
        int2 rv = act ? srn[ee] : make_int2(0, 0);
        float dl = act ? dis[rv.x] : 0.0f;
        float nmL = __int_as_float(rv.y) * dl;  // ew * dis[row]
        int nb = min(64, e_end - bse);
        int j = 0;
        for (; j + 4 <= nb; j += 4) {
            int r0 = __shfl(rv.x, j);
            int r1 = __shfl(rv.x, j + 1);
            int r2 = __shfl(rv.x, j + 2);
            int r3 = __shfl(rv.x, j + 3);
            float n0 = __shfl(nmL, j);
            float n1 = __shfl(nmL, j + 1);
            float n2 = __shfl(nmL, j + 2);
            float n3 = __shfl(nmL, j + 3);
            float2 v0 = x2[(size_t)r0 * 64 + lane];
            float2 v1 = x2[(size_t)r1 * 64 + lane];
            float2 v2 = x2[(size_t)r2 * 64 + lane];
            float2 v3 = x2[(size_t)r3 * 64 + lane];
            acc0.x = fmaf(n0, v0.x, acc0.x); acc0.y = fmaf(n0, v0.y, acc0.y);
            acc1.x = fmaf(n1, v1.x, acc1.x); acc1.y = fmaf(n1, v1.y, acc1.y);
            acc2.x = fmaf(n2, v2.x, acc2.x); acc2.y = fmaf(n2, v2.y, acc2.y);
            acc3.x = fmaf(n3, v3.x, acc3.x); acc3.y = fmaf(n3, v3.y, acc3.y);
        }
        for (; j < nb; ++j) {
            int rr = __shfl(rv.x, j);
            float nm = __shfl(nmL, j);
            float2 v = x2[(size_t)rr * 64 + lane];
            acc0.x = fmaf(nm, v.x, acc0.x); acc0.y = fmaf(nm, v.y, acc0.y);
        }
    }
    acc0.x = dc * (acc0.x + acc1.x + acc2.x + acc3.x);
    acc0.y = dc * (acc0.y + acc1.y + acc2.y + acc3.y);
    ((float2*)agg)[(size_t)node * 64 + lane] = acc0;
}

// ---------------- h = relu(((1-a)*agg + a*x_orig) @ W) ----------------
// No LDS. Block-uniform W reads (scalar-cache path). 1 row/thread x 32 cols.
// grid = (157 row-blocks, 4 col-blocks); 628 blocks -> ~10 waves/CU.
__global__ __launch_bounds__(256) void k_matmul(const float* __restrict__ agg,
                                                const float* __restrict__ xorig,
                                                const float* __restrict__ W,
                                                float* __restrict__ out) {
    int row = blockIdx.x * 256 + threadIdx.x;
    if (row >= NN) return;
    int j0 = blockIdx.y << 5;                 // 32-col slice, block-uniform

    float4 acc[8] = {};                       // cols j0 .. j0+31
    const float* ap = agg + (size_t)row * DD;
    const float* bp = xorig + (size_t)row * DD;

    for (int k0 = 0; k0 < DD; k0 += 4) {
        float4 av = *(const float4*)(ap + k0);
        float4 bv = *(const float4*)(bp + k0);
        float in[4];
        in[0] = 0.9f * av.x + 0.1f * bv.x;
        in[1] = 0.9f * av.y + 0.1f * bv.y;
        in[2] = 0.9f * av.z + 0.1f * bv.z;
        in[3] = 0.9f * av.w + 0.1f * bv.w;
#pragma unroll
        for (int kk = 0; kk < 4; ++kk) {
            const float* wr = W + (size_t)(k0 + kk) * DD + j0;  // uniform address
#pragma unroll
            for (int mp = 0; mp < 8; ++mp) {
                float4 w = *(const float4*)(wr + mp * 4);       // s_load path
                acc[mp].x = fmaf(in[kk], w.x, acc[mp].x);
                acc[mp].y = fmaf(in[kk], w.y, acc[mp].y);
                acc[mp].z = fmaf(in[kk], w.z, acc[mp].z);
                acc[mp].w = fmaf(in[kk], w.w, acc[mp].w);
            }
        }
    }
    float* orow = out + (size_t)row * DD + j0;
#pragma unroll
    for (int mp = 0; mp < 8; ++mp) {
        float4 v = acc[mp];
        v.x = fmaxf(v.x, 0.0f);
        v.y = fmaxf(v.y, 0.0f);
        v.z = fmaxf(v.z, 0.0f);
        v.w = fmaxf(v.w, 0.0f);
        *(float4*)(orow + mp * 4) = v;
    }
}

// ---------------- BN stats: per-column sum & sumsq ----------------
__global__ __launch_bounds__(256) void k_stats(const float* __restrict__ h,
                                               float* __restrict__ sums) {
    int t = threadIdx.x;
    int tid = blockIdx.x * 256 + t;           // 256 blocks
    int cg = t & 31;                          // float4 column group
    int row0 = tid >> 5;                      // 0..2047
    float4 s = {0, 0, 0, 0}, q = {0, 0, 0, 0};
    for (int r = row0; r < NN; r += 2048) {
        float4 v = *(const float4*)&h[(size_t)r * DD + cg * 4];
        s.x += v.x; s.y += v.y; s.z += v.z; s.w += v.w;
        q.x += v.x * v.x; q.y += v.y * v.y; q.z += v.z * v.z; q.w += v.w * v.w;
    }
    __shared__ float red[256][8];
    red[t][0] = s.x; red[t][1] = s.y; red[t][2] = s.z; red[t][3] = s.w;
    red[t][4] = q.x; red[t][5] = q.y; red[t][6] = q.z; red[t][7] = q.w;
    __syncthreads();
    if (t < 32) {
#pragma unroll
        for (int s8 = 1; s8 < 8; ++s8)
#pragma unroll
            for (int c = 0; c < 8; ++c) red[t][c] += red[t + 32 * s8][c];
        int j = t * 4;
        unsafeAtomicAdd(&sums[j + 0], red[t][0]);
        unsafeAtomicAdd(&sums[j + 1], red[t][1]);
        unsafeAtomicAdd(&sums[j + 2], red[t][2]);
        unsafeAtomicAdd(&sums[j + 3], red[t][3]);
        unsafeAtomicAdd(&sums[DD + j + 0], red[t][4]);
        unsafeAtomicAdd(&sums[DD + j + 1], red[t][5]);
        unsafeAtomicAdd(&sums[DD + j + 2], red[t][6]);
        unsafeAtomicAdd(&sums[DD + j + 3], red[t][7]);
    }
}

// ---------------- BN apply (in place on d_out) ----------------
__global__ __launch_bounds__(256) void k_apply(float* __restrict__ h,
                                               const float* __restrict__ sums,
                                               const float* __restrict__ gamma,
                                               const float* __restrict__ beta) {
    int g = blockIdx.x * 256 + threadIdx.x;   // N*32 threads
    int i = g >> 5, q = g & 31;
    int j = q * 4;
    const float invN = 1.0f / (float)NN;
    float4 sm = *(const float4*)&sums[j];
    float4 sq = *(const float4*)&sums[DD + j];
    float4 gm = *(const float4*)&gamma[j];
    float4 bt = *(const float4*)&beta[j];
    float4 v = *(float4*)&h[(size_t)i * DD + j];
    float m0 = sm.x * invN, m1 = sm.y * invN, m2 = sm.z * invN, m3 = sm.w * invN;
    float i0 = rsqrtf(fmaxf(sq.x * invN - m0 * m0, 0.0f) + 1e-5f);
    float i1 = rsqrtf(fmaxf(sq.y * invN - m1 * m1, 0.0f) + 1e-5f);
    float i2 = rsqrtf(fmaxf(sq.z * invN - m2 * m2, 0.0f) + 1e-5f);
    float i3 = rsqrtf(fmaxf(sq.w * invN - m3 * m3, 0.0f) + 1e-5f);
    v.x = (v.x - m0) * i0 * gm.x + bt.x;
    v.y = (v.y - m1) * i1 * gm.y + bt.y;
    v.z = (v.z - m2) * i2 * gm.z + bt.z;
    v.w = (v.w - m3) * i3 * gm.w + bt.w;
    *(float4*)&h[(size_t)i * DD + j] = v;
}

extern "C" void kernel_launch(void* const* d_in, const int* in_sizes, int n_in,
                              void* d_out, int out_size, void* d_ws, size_t ws_size,
                              hipStream_t stream) {
    const float* x     = (const float*)d_in[0];
    const float* xorig = (const float*)d_in[1];
    const int*   ei    = (const int*)d_in[2];
    const float* ew    = (const float*)d_in[3];
    const float* W     = (const float*)d_in[4];
    const float* gamma = (const float*)d_in[5];
    const float* beta  = (const float*)d_in[6];
    float* out = (float*)d_out;

    // workspace layout (agg first keeps 8B alignment for srn)
    float* ws   = (float*)d_ws;
    float* agg  = ws;                              // N*D floats
    int2*  srn  = (int2*)(agg + (size_t)NN * DD);  // E int2 (row, ew-bits)
    float* dis  = (float*)(srn + EE);              // N floats
    float* sums = dis + NN;                        // 256 floats
    int*   cnt  = (int*)(sums + 256);              // N
    int*   off  = cnt + NN;                        // N+1
    int*   rank = off + NN + 1;                    // E

    k_init   <<<160,   256, 0, stream>>>(cnt, sums);
    k_rank   <<<2500,  256, 0, stream>>>(ei, cnt, rank);
    k_scan   <<<1,    1024, 0, stream>>>(cnt, off);
    k_permute<<<2500,  256, 0, stream>>>(ei, ew, rank, off, srn);
    k_degdis <<<10000, 256, 0, stream>>>(off, srn, dis);
    k_gather <<<10000, 256, 0, stream>>>(off, srn, x, dis, agg);
    k_matmul <<<dim3(157, 4), 256, 0, stream>>>(agg, xorig, W, out);
    k_stats  <<<256,   256, 0, stream>>>(out, sums);
    k_apply  <<<5000,  256, 0, stream>>>(out, sums, gamma, beta);
}

// Round 10
// 328.658 us; speedup vs baseline: 1.0147x; 1.0147x over previous
//
#include <hip/hip_runtime.h>

#define NN 40000
#define DD 128
#define EE 640000

// ---------------- init: cnt = 0, zero BN sums ----------------
__global__ __launch_bounds__(256) void k_init(int* __restrict__ cnt,
                                              float* __restrict__ sums) {
    int i = blockIdx.x * 256 + threadIdx.x;
    if (i < NN) cnt[i] = 0;
    if (i < 256) sums[i] = 0.0f;   // 128 sum + 128 sumsq
}

// ---------------- rank[e] = cnt[col]++  (the ONLY atomic pass) ----------------
__global__ __launch_bounds__(256) void k_rank(const int* __restrict__ ei,
                                              int* __restrict__ cnt,
                                              int* __restrict__ rank) {
    int e = blockIdx.x * 256 + threadIdx.x;   // E = 2500*256 exactly
    int c = ei[EE + e];
    rank[e] = atomicAdd(&cnt[c], 1);
}

// ---------------- exclusive scan of cnt -> off (single block) ----------------
#define SCAN_CH 40
__global__ __launch_bounds__(1024) void k_scan(const int* __restrict__ cnt,
                                               int* __restrict__ off) {
    __shared__ int sm[1024];
    int t = threadIdx.x;
    int base = t * SCAN_CH;                   // 1000 threads cover 40000 exactly
    int s = 0;
    if (base < NN) {
#pragma unroll
        for (int i = 0; i < SCAN_CH; ++i) s += cnt[base + i];
    }
    sm[t] = s;
    __syncthreads();
    for (int d = 1; d < 1024; d <<= 1) {      // Hillis-Steele inclusive scan
        int v = (t >= d) ? sm[t - d] : 0;
        __syncthreads();
        sm[t] += v;
        __syncthreads();
    }
    if (base < NN) {
        int run = sm[t] - s;                  // exclusive base for this chunk
#pragma unroll
        for (int i = 0; i < SCAN_CH; ++i) {
            off[base + i] = run;
            run += cnt[base + i];
        }
    }
    if (t == 1023) off[NN] = sm[1023];        // == EE
}

// ---------------- permute edges into dest-sorted order (NO atomics) ----------------
__global__ __launch_bounds__(256) void k_permute(const int* __restrict__ ei,
                                                 const float* __restrict__ ew,
                                                 const int* __restrict__ rank,
                                                 const int* __restrict__ off,
                                                 int2* __restrict__ srn) {
    int e = blockIdx.x * 256 + threadIdx.x;   // 2500 blocks
    int r = ei[e], c = ei[EE + e];
    int pos = off[c] + rank[e];
    srn[pos] = make_int2(r, __float_as_int(ew[e]));
}

// ---------------- deg from CSR segments: dis = rsqrt(1 + sum ew), wave/node ----------------
__global__ __launch_bounds__(256) void k_degdis(const int* __restrict__ off,
                                                const int2* __restrict__ srn,
                                                float* __restrict__ dis) {
    int gid = blockIdx.x * 256 + threadIdx.x; // 10000 blocks -> 40000 waves
    int node = gid >> 6;
    int lane = gid & 63;
    int s = off[node], e = off[node + 1];
    float v = 0.0f;
    for (int p = s + lane; p < e; p += 64) v += __int_as_float(srn[p].y);
#pragma unroll
    for (int m = 1; m < 64; m <<= 1) v += __shfl_xor(v, m);
    if (lane == 0) dis[node] = rsqrtf(1.0f + v);
}

// ---------------- gather: one wave per node, norm computed on the fly ----------------
// 4-wide edge unroll: 4 independent x-row loads in flight per iter.
__global__ __launch_bounds__(256) void k_gather(const int* __restrict__ off,
                                                const int2* __restrict__ srn,
                                                const float* __restrict__ x,
                                                const float* __restrict__ dis,
                                                float* __restrict__ agg) {
    int gid = blockIdx.x * 256 + threadIdx.x; // 10000 blocks -> 40000 waves
    int node = gid >> 6;
    int lane = gid & 63;
    const float2* x2 = (const float2*)x;
    float dc = dis[node];
    float2 sv = x2[(size_t)node * 64 + lane];
    float2 acc0 = {sv.x * dc, sv.y * dc};     // self term: dc*(dc*x_c) after final scale
    float2 acc1 = {0.f, 0.f}, acc2 = {0.f, 0.f}, acc3 = {0.f, 0.f};
    int s = off[node], e_end = off[node + 1];
    for (int bse = s; bse < e_end; bse += 64) {
        int ee = bse + lane;
        bool act = (ee < e_end);
        int2 rv = act ? srn[ee] : make_int2(0, 0);
        float dl = act ? dis[rv.x] : 0.0f;
        float nmL = __int_as_float(rv.y) * dl;  // ew * dis[row]
        int nb = min(64, e_end - bse);
        int j = 0;
        for (; j + 4 <= nb; j += 4) {
            int r0 = __shfl(rv.x, j);
            int r1 = __shfl(rv.x, j + 1);
            int r2 = __shfl(rv.x, j + 2);
            int r3 = __shfl(rv.x, j + 3);
            float n0 = __shfl(nmL, j);
            float n1 = __shfl(nmL, j + 1);
            float n2 = __shfl(nmL, j + 2);
            float n3 = __shfl(nmL, j + 3);
            float2 v0 = x2[(size_t)r0 * 64 + lane];
            float2 v1 = x2[(size_t)r1 * 64 + lane];
            float2 v2 = x2[(size_t)r2 * 64 + lane];
            float2 v3 = x2[(size_t)r3 * 64 + lane];
            acc0.x = fmaf(n0, v0.x, acc0.x); acc0.y = fmaf(n0, v0.y, acc0.y);
            acc1.x = fmaf(n1, v1.x, acc1.x); acc1.y = fmaf(n1, v1.y, acc1.y);
            acc2.x = fmaf(n2, v2.x, acc2.x); acc2.y = fmaf(n2, v2.y, acc2.y);
            acc3.x = fmaf(n3, v3.x, acc3.x); acc3.y = fmaf(n3, v3.y, acc3.y);
        }
        for (; j < nb; ++j) {
            int rr = __shfl(rv.x, j);
            float nm = __shfl(nmL, j);
            float2 v = x2[(size_t)rr * 64 + lane];
            acc0.x = fmaf(nm, v.x, acc0.x); acc0.y = fmaf(nm, v.y, acc0.y);
        }
    }
    acc0.x = dc * (acc0.x + acc1.x + acc2.x + acc3.x);
    acc0.y = dc * (acc0.y + acc1.y + acc2.y + acc3.y);
    ((float2*)agg)[(size_t)node * 64 + lane] = acc0;
}

// ---------------- h = relu(((1-a)*agg + a*x_orig) @ W) ----------------
// 64 rows/block -> 625 blocks (~10 waves/CU). Blended input staged TRANSPOSED
// in 32KB LDS (conflict-free both sides). Wave w owns col-slice j0=w*32 so
// W loads are wave-uniform (one broadcast fetch per float4). Rows read ONCE.
__global__ __launch_bounds__(256) void k_matmul(const float* __restrict__ agg,
                                                const float* __restrict__ xorig,
                                                const float* __restrict__ W,
                                                float* __restrict__ out) {
    __shared__ float lds_in[DD * 64];         // [k][row] 32 KB
    int t = threadIdx.x;
    int r0 = blockIdx.x * 64;                 // 625 blocks * 64 rows = 40000

    {   // stage: thread (rl = t&63, kq = t>>6) blends rows into lds_in[k][rl]
        int rl = t & 63, kq = t >> 6;
        const float* ap = agg   + (size_t)(r0 + rl) * DD + kq * 32;
        const float* bp = xorig + (size_t)(r0 + rl) * DD + kq * 32;
#pragma unroll
        for (int i = 0; i < 8; ++i) {         // 8 float4 = 32 k each
            float4 av = *(const float4*)(ap + i * 4);
            float4 bv = *(const float4*)(bp + i * 4);
            int kb = kq * 32 + i * 4;
            lds_in[(kb + 0) * 64 + rl] = 0.9f * av.x + 0.1f * bv.x;
            lds_in[(kb + 1) * 64 + rl] = 0.9f * av.y + 0.1f * bv.y;
            lds_in[(kb + 2) * 64 + rl] = 0.9f * av.z + 0.1f * bv.z;
            lds_in[(kb + 3) * 64 + rl] = 0.9f * av.w + 0.1f * bv.w;
        }
    }
    __syncthreads();

    int l = t & 63;                           // lane = row
    int j0 = (t >> 6) * 32;                   // wave-uniform col-slice

    float4 acc[8] = {};
    for (int k0 = 0; k0 < DD; k0 += 4) {
        float in0 = lds_in[(k0 + 0) * 64 + l];
        float in1 = lds_in[(k0 + 1) * 64 + l];
        float in2 = lds_in[(k0 + 2) * 64 + l];
        float in3 = lds_in[(k0 + 3) * 64 + l];
        float in[4] = {in0, in1, in2, in3};
#pragma unroll
        for (int kk = 0; kk < 4; ++kk) {
            const float* wr = W + (size_t)(k0 + kk) * DD + j0;  // uniform addr
#pragma unroll
            for (int mp = 0; mp < 8; ++mp) {
                float4 w = *(const float4*)(wr + mp * 4);       // broadcast
                acc[mp].x = fmaf(in[kk], w.x, acc[mp].x);
                acc[mp].y = fmaf(in[kk], w.y, acc[mp].y);
                acc[mp].z = fmaf(in[kk], w.z, acc[mp].z);
                acc[mp].w = fmaf(in[kk], w.w, acc[mp].w);
            }
        }
    }
    float* orow = out + (size_t)(r0 + l) * DD + j0;
#pragma unroll
    for (int mp = 0; mp < 8; ++mp) {
        float4 v = acc[mp];
        v.x = fmaxf(v.x, 0.0f);
        v.y = fmaxf(v.y, 0.0f);
        v.z = fmaxf(v.z, 0.0f);
        v.w = fmaxf(v.w, 0.0f);
        *(float4*)(orow + mp * 4) = v;
    }
}

// ---------------- BN stats: per-column sum & sumsq ----------------
__global__ __launch_bounds__(256) void k_stats(const float* __restrict__ h,
                                               float* __restrict__ sums) {
    int t = threadIdx.x;
    int tid = blockIdx.x * 256 + t;           // 256 blocks
    int cg = t & 31;                          // float4 column group
    int row0 = tid >> 5;                      // 0..2047
    float4 s = {0, 0, 0, 0}, q = {0, 0, 0, 0};
    for (int r = row0; r < NN; r += 2048) {
        float4 v = *(const float4*)&h[(size_t)r * DD + cg * 4];
        s.x += v.x; s.y += v.y; s.z += v.z; s.w += v.w;
        q.x += v.x * v.x; q.y += v.y * v.y; q.z += v.z * v.z; q.w += v.w * v.w;
    }
    __shared__ float red[256][8];
    red[t][0] = s.x; red[t][1] = s.y; red[t][2] = s.z; red[t][3] = s.w;
    red[t][4] = q.x; red[t][5] = q.y; red[t][6] = q.z; red[t][7] = q.w;
    __syncthreads();
    if (t < 32) {
#pragma unroll
        for (int s8 = 1; s8 < 8; ++s8)
#pragma unroll
            for (int c = 0; c < 8; ++c) red[t][c] += red[t + 32 * s8][c];
        int j = t * 4;
        unsafeAtomicAdd(&sums[j + 0], red[t][0]);
        unsafeAtomicAdd(&sums[j + 1], red[t][1]);
        unsafeAtomicAdd(&sums[j + 2], red[t][2]);
        unsafeAtomicAdd(&sums[j + 3], red[t][3]);
        unsafeAtomicAdd(&sums[DD + j + 0], red[t][4]);
        unsafeAtomicAdd(&sums[DD + j + 1], red[t][5]);
        unsafeAtomicAdd(&sums[DD + j + 2], red[t][6]);
        unsafeAtomicAdd(&sums[DD + j + 3], red[t][7]);
    }
}

// ---------------- BN apply (in place on d_out) ----------------
__global__ __launch_bounds__(256) void k_apply(float* __restrict__ h,
                                               const float* __restrict__ sums,
                                               const float* __restrict__ gamma,
                                               const float* __restrict__ beta) {
    int g = blockIdx.x * 256 + threadIdx.x;   // N*32 threads
    int i = g >> 5, q = g & 31;
    int j = q * 4;
    const float invN = 1.0f / (float)NN;
    float4 sm = *(const float4*)&sums[j];
    float4 sq = *(const float4*)&sums[DD + j];
    float4 gm = *(const float4*)&gamma[j];
    float4 bt = *(const float4*)&beta[j];
    float4 v = *(float4*)&h[(size_t)i * DD + j];
    float m0 = sm.x * invN, m1 = sm.y * invN, m2 = sm.z * invN, m3 = sm.w * invN;
    float i0 = rsqrtf(fmaxf(sq.x * invN - m0 * m0, 0.0f) + 1e-5f);
    float i1 = rsqrtf(fmaxf(sq.y * invN - m1 * m1, 0.0f) + 1e-5f);
    float i2 = rsqrtf(fmaxf(sq.z * invN - m2 * m2, 0.0f) + 1e-5f);
    float i3 = rsqrtf(fmaxf(sq.w * invN - m3 * m3, 0.0f) + 1e-5f);
    v.x = (v.x - m0) * i0 * gm.x + bt.x;
    v.y = (v.y - m1) * i1 * gm.y + bt.y;
    v.z = (v.z - m2) * i2 * gm.z + bt.z;
    v.w = (v.w - m3) * i3 * gm.w + bt.w;
    *(float4*)&h[(size_t)i * DD + j] = v;
}

extern "C" void kernel_launch(void* const* d_in, const int* in_sizes, int n_in,
                              void* d_out, int out_size, void* d_ws, size_t ws_size,
                              hipStream_t stream) {
    const float* x     = (const float*)d_in[0];
    const float* xorig = (const float*)d_in[1];
    const int*   ei    = (const int*)d_in[2];
    const float* ew    = (const float*)d_in[3];
    const float* W     = (const float*)d_in[4];
    const float* gamma = (const float*)d_in[5];
    const float* beta  = (const float*)d_in[6];
    float* out = (float*)d_out;

    // workspace layout (agg first keeps 8B alignment for srn)
    float* ws   = (float*)d_ws;
    float* agg  = ws;                              // N*D floats
    int2*  srn  = (int2*)(agg + (size_t)NN * DD);  // E int2 (row, ew-bits)
    float* dis  = (float*)(srn + EE);              // N floats
    float* sums = dis + NN;                        // 256 floats
    int*   cnt  = (int*)(sums + 256);              // N
    int*   off  = cnt + NN;                        // N+1
    int*   rank = off + NN + 1;                    // E

    k_init   <<<160,   256, 0, stream>>>(cnt, sums);
    k_rank   <<<2500,  256, 0, stream>>>(ei, cnt, rank);
    k_scan   <<<1,    1024, 0, stream>>>(cnt, off);
    k_permute<<<2500,  256, 0, stream>>>(ei, ew, rank, off, srn);
    k_degdis <<<10000, 256, 0, stream>>>(off, srn, dis);
    k_gather <<<10000, 256, 0, stream>>>(off, srn, x, dis, agg);
    k_matmul <<<625,   256, 0, stream>>>(agg, xorig, W, out);
    k_stats  <<<256,   256, 0, stream>>>(out, sums);
    k_apply  <<<5000,  256, 0, stream>>>(out, sums, gamma, beta);
}

// Round 11
// 288.292 us; speedup vs baseline: 1.1568x; 1.1400x over previous
//
#include <hip/hip_runtime.h>

#define NN 40000
#define DD 128
#define EE 640000

// ---------------- init: cnt = 0, zero BN sums ----------------
__global__ __launch_bounds__(256) void k_init(int* __restrict__ cnt,
                                              float* __restrict__ sums) {
    int i = blockIdx.x * 256 + threadIdx.x;
    if (i < NN) cnt[i] = 0;
    if (i < 256) sums[i] = 0.0f;   // 128 sum + 128 sumsq
}

// ---------------- rank[e] = cnt[col]++  (the ONLY atomic pass) ----------------
__global__ __launch_bounds__(256) void k_rank(const int* __restrict__ ei,
                                              int* __restrict__ cnt,
                                              int* __restrict__ rank) {
    int e = blockIdx.x * 256 + threadIdx.x;   // E = 2500*256 exactly
    int c = ei[EE + e];
    rank[e] = atomicAdd(&cnt[c], 1);
}

// ---------------- exclusive scan of cnt -> off (single block) ----------------
#define SCAN_CH 40
__global__ __launch_bounds__(1024) void k_scan(const int* __restrict__ cnt,
                                               int* __restrict__ off) {
    __shared__ int sm[1024];
    int t = threadIdx.x;
    int base = t * SCAN_CH;                   // 1000 threads cover 40000 exactly
    int s = 0;
    if (base < NN) {
#pragma unroll
        for (int i = 0; i < SCAN_CH; ++i) s += cnt[base + i];
    }
    sm[t] = s;
    __syncthreads();
    for (int d = 1; d < 1024; d <<= 1) {      // Hillis-Steele inclusive scan
        int v = (t >= d) ? sm[t - d] : 0;
        __syncthreads();
        sm[t] += v;
        __syncthreads();
    }
    if (base < NN) {
        int run = sm[t] - s;                  // exclusive base for this chunk
#pragma unroll
        for (int i = 0; i < SCAN_CH; ++i) {
            off[base + i] = run;
            run += cnt[base + i];
        }
    }
    if (t == 1023) off[NN] = sm[1023];        // == EE
}

// ---------------- permute edges into dest-sorted order (NO atomics) ----------------
__global__ __launch_bounds__(256) void k_permute(const int* __restrict__ ei,
                                                 const float* __restrict__ ew,
                                                 const int* __restrict__ rank,
                                                 const int* __restrict__ off,
                                                 int2* __restrict__ srn) {
    int e = blockIdx.x * 256 + threadIdx.x;   // 2500 blocks
    int r = ei[e], c = ei[EE + e];
    int pos = off[c] + rank[e];
    srn[pos] = make_int2(r, __float_as_int(ew[e]));
}

// ---------------- deg from CSR segments: dis = rsqrt(1 + sum ew), wave/node ----------------
__global__ __launch_bounds__(256) void k_degdis(const int* __restrict__ off,
                                                const int2* __restrict__ srn,
                                                float* __restrict__ dis) {
    int gid = blockIdx.x * 256 + threadIdx.x; // 10000 blocks -> 40000 waves
    int node = gid >> 6;
    int lane = gid & 63;
    int s = off[node], e = off[node + 1];
    float v = 0.0f;
    for (int p = s + lane; p < e; p += 64) v += __int_as_float(srn[p].y);
#pragma unroll
    for (int m = 1; m < 64; m <<= 1) v += __shfl_xor(v, m);
    if (lane == 0) dis[node] = rsqrtf(1.0f + v);
}

// ---------------- gather: TWO nodes per wave (lane halves), float4 lanes ----------------
// Per edge-broadcast iteration one load instruction fetches 2 rows (one per half)
// -> 2x independent latency chains, half the instruction stream per edge.
__global__ __launch_bounds__(256) void k_gather(const int* __restrict__ off,
                                                const int2* __restrict__ srn,
                                                const float* __restrict__ x,
                                                const float* __restrict__ dis,
                                                float* __restrict__ agg) {
    int gid = blockIdx.x * 256 + threadIdx.x; // 5000 blocks -> 20000 waves
    int wave = gid >> 6;
    int lane = gid & 63;
    int half = lane >> 5;                     // 0/1: which node this lane serves
    int l32  = lane & 31;                     // float4 slot within the row
    int node = wave * 2 + half;               // 20000*2 = 40000 exactly
    int srcb = half << 5;                     // shfl source base for own half
    const float4* x4 = (const float4*)x;

    float dc = dis[node];
    float4 sv = x4[(size_t)node * 32 + l32];
    float4 acc0 = {sv.x * dc, sv.y * dc, sv.z * dc, sv.w * dc};
    float4 acc1 = {0, 0, 0, 0}, acc2 = {0, 0, 0, 0}, acc3 = {0, 0, 0, 0};

    int p = off[node], eend = off[node + 1];
    while (__any(p < eend)) {                 // wave-uniform loop, no divergence here
        int ee = p + l32;
        bool act = ee < eend;
        int2 rv = act ? srn[ee] : make_int2(0, 0);
        float dl = act ? dis[rv.x] : 0.0f;
        float nm = __int_as_float(rv.y) * dl; // ew * dis[row]
        int nb = eend - p;
        nb = nb < 0 ? 0 : (nb > 32 ? 32 : nb);
        int j = 0;
        for (; j + 4 <= nb; j += 4) {
            int r0 = __shfl(rv.x, srcb + j);
            int r1 = __shfl(rv.x, srcb + j + 1);
            int r2 = __shfl(rv.x, srcb + j + 2);
            int r3 = __shfl(rv.x, srcb + j + 3);
            float n0 = __shfl(nm, srcb + j);
            float n1 = __shfl(nm, srcb + j + 1);
            float n2 = __shfl(nm, srcb + j + 2);
            float n3 = __shfl(nm, srcb + j + 3);
            float4 v0 = x4[(size_t)r0 * 32 + l32];
            float4 v1 = x4[(size_t)r1 * 32 + l32];
            float4 v2 = x4[(size_t)r2 * 32 + l32];
            float4 v3 = x4[(size_t)r3 * 32 + l32];
            acc0.x = fmaf(n0, v0.x, acc0.x); acc0.y = fmaf(n0, v0.y, acc0.y);
            acc0.z = fmaf(n0, v0.z, acc0.z); acc0.w = fmaf(n0, v0.w, acc0.w);
            acc1.x = fmaf(n1, v1.x, acc1.x); acc1.y = fmaf(n1, v1.y, acc1.y);
            acc1.z = fmaf(n1, v1.z, acc1.z); acc1.w = fmaf(n1, v1.w, acc1.w);
            acc2.x = fmaf(n2, v2.x, acc2.x); acc2.y = fmaf(n2, v2.y, acc2.y);
            acc2.z = fmaf(n2, v2.z, acc2.z); acc2.w = fmaf(n2, v2.w, acc2.w);
            acc3.x = fmaf(n3, v3.x, acc3.x); acc3.y = fmaf(n3, v3.y, acc3.y);
            acc3.z = fmaf(n3, v3.z, acc3.z); acc3.w = fmaf(n3, v3.w, acc3.w);
        }
        for (; j < nb; ++j) {
            int rr = __shfl(rv.x, srcb + j);
            float nn = __shfl(nm, srcb + j);
            float4 v = x4[(size_t)rr * 32 + l32];
            acc0.x = fmaf(nn, v.x, acc0.x); acc0.y = fmaf(nn, v.y, acc0.y);
            acc0.z = fmaf(nn, v.z, acc0.z); acc0.w = fmaf(nn, v.w, acc0.w);
        }
        p += 32;
    }
    acc0.x = dc * (acc0.x + acc1.x + acc2.x + acc3.x);
    acc0.y = dc * (acc0.y + acc1.y + acc2.y + acc3.y);
    acc0.z = dc * (acc0.z + acc1.z + acc2.z + acc3.z);
    acc0.w = dc * (acc0.w + acc1.w + acc2.w + acc3.w);
    ((float4*)agg)[(size_t)node * 32 + l32] = acc0;
}

// ---------------- h = relu(((1-a)*agg + a*x_orig) @ W), 4 rows/thread ----------------
// W half-tile [128][64] = 32 KB LDS; grid (313, 2) = 626 blocks (~10 waves/CU).
// Per thread: 4 rows x 8 cols. LDS reads are broadcast/2-way (free).
__global__ __launch_bounds__(256) void k_matmul(const float* __restrict__ agg,
                                                const float* __restrict__ xorig,
                                                const float* __restrict__ W,
                                                float* __restrict__ out) {
    __shared__ float Wl[DD * 64];             // [k][c] 32 KB
    int t = threadIdx.x;
    int jb = blockIdx.y << 6;                 // col-half base (0 or 64)
    {   // stage W[:, jb:jb+64]: 2048 float4, 8 per thread
#pragma unroll
        for (int i = 0; i < 8; ++i) {
            int idx = i * 256 + t;
            int k = idx >> 4, jq = idx & 15;
            *(float4*)&Wl[k * 64 + jq * 4] =
                *(const float4*)&W[(size_t)k * DD + jb + jq * 4];
        }
    }
    __syncthreads();

    int rg = t >> 3;                          // 32 row-groups of 4 rows
    int cg = t & 7;                           // 8 col-groups of 8 cols
    int row0 = blockIdx.x * 128 + rg * 4;     // 313*128 = 40064 (tail guarded)
    bool valid = (row0 + 3) < NN;
    size_t rr = valid ? (size_t)row0 : 0;
    int jc = cg * 8;

    float acc[4][8] = {};
    const float* ap = agg + rr * DD;
    const float* bp = xorig + rr * DD;

    for (int k0 = 0; k0 < DD; k0 += 4) {
        float in[4][4];
#pragma unroll
        for (int r = 0; r < 4; ++r) {
            float4 av = *(const float4*)(ap + r * DD + k0);
            float4 bv = *(const float4*)(bp + r * DD + k0);
            in[r][0] = 0.9f * av.x + 0.1f * bv.x;
            in[r][1] = 0.9f * av.y + 0.1f * bv.y;
            in[r][2] = 0.9f * av.z + 0.1f * bv.z;
            in[r][3] = 0.9f * av.w + 0.1f * bv.w;
        }
#pragma unroll
        for (int kk = 0; kk < 4; ++kk) {
            float4 w0 = *(const float4*)&Wl[(k0 + kk) * 64 + jc];
            float4 w1 = *(const float4*)&Wl[(k0 + kk) * 64 + jc + 4];
#pragma unroll
            for (int r = 0; r < 4; ++r) {
                float a = in[r][kk];
                acc[r][0] = fmaf(a, w0.x, acc[r][0]);
                acc[r][1] = fmaf(a, w0.y, acc[r][1]);
                acc[r][2] = fmaf(a, w0.z, acc[r][2]);
                acc[r][3] = fmaf(a, w0.w, acc[r][3]);
                acc[r][4] = fmaf(a, w1.x, acc[r][4]);
                acc[r][5] = fmaf(a, w1.y, acc[r][5]);
                acc[r][6] = fmaf(a, w1.z, acc[r][6]);
                acc[r][7] = fmaf(a, w1.w, acc[r][7]);
            }
        }
    }
    if (valid) {
#pragma unroll
        for (int r = 0; r < 4; ++r) {
            float* orow = out + (rr + r) * DD + jb + jc;
            float4 v0 = {fmaxf(acc[r][0], 0.0f), fmaxf(acc[r][1], 0.0f),
                         fmaxf(acc[r][2], 0.0f), fmaxf(acc[r][3], 0.0f)};
            float4 v1 = {fmaxf(acc[r][4], 0.0f), fmaxf(acc[r][5], 0.0f),
                         fmaxf(acc[r][6], 0.0f), fmaxf(acc[r][7], 0.0f)};
            *(float4*)(orow) = v0;
            *(float4*)(orow + 4) = v1;
        }
    }
}

// ---------------- BN stats: per-column sum & sumsq ----------------
__global__ __launch_bounds__(256) void k_stats(const float* __restrict__ h,
                                               float* __restrict__ sums) {
    int t = threadIdx.x;
    int tid = blockIdx.x * 256 + t;           // 256 blocks
    int cg = t & 31;                          // float4 column group
    int row0 = tid >> 5;                      // 0..2047
    float4 s = {0, 0, 0, 0}, q = {0, 0, 0, 0};
    for (int r = row0; r < NN; r += 2048) {
        float4 v = *(const float4*)&h[(size_t)r * DD + cg * 4];
        s.x += v.x; s.y += v.y; s.z += v.z; s.w += v.w;
        q.x += v.x * v.x; q.y += v.y * v.y; q.z += v.z * v.z; q.w += v.w * v.w;
    }
    __shared__ float red[256][8];
    red[t][0] = s.x; red[t][1] = s.y; red[t][2] = s.z; red[t][3] = s.w;
    red[t][4] = q.x; red[t][5] = q.y; red[t][6] = q.z; red[t][7] = q.w;
    __syncthreads();
    if (t < 32) {
#pragma unroll
        for (int s8 = 1; s8 < 8; ++s8)
#pragma unroll
            for (int c = 0; c < 8; ++c) red[t][c] += red[t + 32 * s8][c];
        int j = t * 4;
        unsafeAtomicAdd(&sums[j + 0], red[t][0]);
        unsafeAtomicAdd(&sums[j + 1], red[t][1]);
        unsafeAtomicAdd(&sums[j + 2], red[t][2]);
        unsafeAtomicAdd(&sums[j + 3], red[t][3]);
        unsafeAtomicAdd(&sums[DD + j + 0], red[t][4]);
        unsafeAtomicAdd(&sums[DD + j + 1], red[t][5]);
        unsafeAtomicAdd(&sums[DD + j + 2], red[t][6]);
        unsafeAtomicAdd(&sums[DD + j + 3], red[t][7]);
    }
}

// ---------------- BN apply (in place on d_out) ----------------
__global__ __launch_bounds__(256) void k_apply(float* __restrict__ h,
                                               const float* __restrict__ sums,
                                               const float* __restrict__ gamma,
                                               const float* __restrict__ beta) {
    int g = blockIdx.x * 256 + threadIdx.x;   // N*32 threads
    int i = g >> 5, q = g & 31;
    int j = q * 4;
    const float invN = 1.0f / (float)NN;
    float4 sm = *(const float4*)&sums[j];
    float4 sq = *(const float4*)&sums[DD + j];
    float4 gm = *(const float4*)&gamma[j];
    float4 bt = *(const float4*)&beta[j];
    float4 v = *(float4*)&h[(size_t)i * DD + j];
    float m0 = sm.x * invN, m1 = sm.y * invN, m2 = sm.z * invN, m3 = sm.w * invN;
    float i0 = rsqrtf(fmaxf(sq.x * invN - m0 * m0, 0.0f) + 1e-5f);
    float i1 = rsqrtf(fmaxf(sq.y * invN - m1 * m1, 0.0f) + 1e-5f);
    float i2 = rsqrtf(fmaxf(sq.z * invN - m2 * m2, 0.0f) + 1e-5f);
    float i3 = rsqrtf(fmaxf(sq.w * invN - m3 * m3, 0.0f) + 1e-5f);
    v.x = (v.x - m0) * i0 * gm.x + bt.x;
    v.y = (v.y - m1) * i1 * gm.y + bt.y;
    v.z = (v.z - m2) * i2 * gm.z + bt.z;
    v.w = (v.w - m3) * i3 * gm.w + bt.w;
    *(float4*)&h[(size_t)i * DD + j] = v;
}

extern "C" void kernel_launch(void* const* d_in, const int* in_sizes, int n_in,
                              void* d_out, int out_size, void* d_ws, size_t ws_size,
                              hipStream_t stream) {
    const float* x     = (const float*)d_in[0];
    const float* xorig = (const float*)d_in[1];
    const int*   ei    = (const int*)d_in[2];
    const float* ew    = (const float*)d_in[3];
    const float* W     = (const float*)d_in[4];
    const float* gamma = (const float*)d_in[5];
    const float* beta  = (const float*)d_in[6];
    float* out = (float*)d_out;

    // workspace layout (agg first keeps 16B alignment for float4 & srn)
    float* ws   = (float*)d_ws;
    float* agg  = ws;                              // N*D floats
    int2*  srn  = (int2*)(agg + (size_t)NN * DD);  // E int2 (row, ew-bits)
    float* dis  = (float*)(srn + EE);              // N floats
    float* sums = dis + NN;                        // 256 floats
    int*   cnt  = (int*)(sums + 256);              // N
    int*   off  = cnt + NN;                        // N+1
    int*   rank = off + NN + 1;                    // E

    k_init   <<<160,   256, 0, stream>>>(cnt, sums);
    k_rank   <<<2500,  256, 0, stream>>>(ei, cnt, rank);
    k_scan   <<<1,    1024, 0, stream>>>(cnt, off);
    k_permute<<<2500,  256, 0, stream>>>(ei, ew, rank, off, srn);
    k_degdis <<<10000, 256, 0, stream>>>(off, srn, dis);
    k_gather <<<5000,  256, 0, stream>>>(off, srn, x, dis, agg);
    k_matmul <<<dim3(313, 2), 256, 0, stream>>>(agg, xorig, W, out);
    k_stats  <<<256,   256, 0, stream>>>(out, sums);
    k_apply  <<<5000,  256, 0, stream>>>(out, sums, gamma, beta);
}

// Round 14
// 257.927 us; speedup vs baseline: 1.2930x; 1.1177x over previous
//
#include <hip/hip_runtime.h>

#define NN 40000
#define DD 128
#define EE 640000

// ---------------- init: cnt = 0, zero BN sums ----------------
__global__ __launch_bounds__(256) void k_init(int* __restrict__ cnt,
                                              float* __restrict__ sums) {
    int i = blockIdx.x * 256 + threadIdx.x;
    if (i < NN) cnt[i] = 0;
    if (i < 256) sums[i] = 0.0f;   // 128 sum + 128 sumsq
}

// ---------------- rank[e] = cnt[col]++  (the ONLY atomic pass) ----------------
__global__ __launch_bounds__(256) void k_rank(const int* __restrict__ ei,
                                              int* __restrict__ cnt,
                                              int* __restrict__ rank) {
    int e = blockIdx.x * 256 + threadIdx.x;   // E = 2500*256 exactly
    int c = ei[EE + e];
    rank[e] = atomicAdd(&cnt[c], 1);
}

// ---------------- exclusive scan of cnt -> off (single block) ----------------
#define SCAN_CH 40
__global__ __launch_bounds__(1024) void k_scan(const int* __restrict__ cnt,
                                               int* __restrict__ off) {
    __shared__ int sm[1024];
    int t = threadIdx.x;
    int base = t * SCAN_CH;                   // 1000 threads cover 40000 exactly
    int s = 0;
    if (base < NN) {
#pragma unroll
        for (int i = 0; i < SCAN_CH; ++i) s += cnt[base + i];
    }
    sm[t] = s;
    __syncthreads();
    for (int d = 1; d < 1024; d <<= 1) {      // Hillis-Steele inclusive scan
        int v = (t >= d) ? sm[t - d] : 0;
        __syncthreads();
        sm[t] += v;
        __syncthreads();
    }
    if (base < NN) {
        int run = sm[t] - s;                  // exclusive base for this chunk
#pragma unroll
        for (int i = 0; i < SCAN_CH; ++i) {
            off[base + i] = run;
            run += cnt[base + i];
        }
    }
    if (t == 1023) off[NN] = sm[1023];        // == EE
}

// ---------------- permute edges into dest-sorted order (NO atomics) ----------------
__global__ __launch_bounds__(256) void k_permute(const int* __restrict__ ei,
                                                 const float* __restrict__ ew,
                                                 const int* __restrict__ rank,
                                                 const int* __restrict__ off,
                                                 int2* __restrict__ srn) {
    int e = blockIdx.x * 256 + threadIdx.x;   // 2500 blocks
    int r = ei[e], c = ei[EE + e];
    int pos = off[c] + rank[e];
    srn[pos] = make_int2(r, __float_as_int(ew[e]));
}

// ---------------- deg from CSR segments: dis = rsqrt(1 + sum ew), wave/node ----------------
__global__ __launch_bounds__(256) void k_degdis(const int* __restrict__ off,
                                                const int2* __restrict__ srn,
                                                float* __restrict__ dis) {
    int gid = blockIdx.x * 256 + threadIdx.x; // 10000 blocks -> 40000 waves
    int node = gid >> 6;
    int lane = gid & 63;
    int s = off[node], e = off[node + 1];
    float v = 0.0f;
    for (int p = s + lane; p < e; p += 64) v += __int_as_float(srn[p].y);
#pragma unroll
    for (int m = 1; m < 64; m <<= 1) v += __shfl_xor(v, m);
    if (lane == 0) dis[node] = rsqrtf(1.0f + v);
}

// ---------------- gather: TWO nodes per wave, blend FUSED into epilogue ----------------
// blend[node] = 0.9 * dc*(dc*x_c + sum nm*x_r) + 0.1 * xorig[node]
__global__ __launch_bounds__(256) void k_gather(const int* __restrict__ off,
                                                const int2* __restrict__ srn,
                                                const float* __restrict__ x,
                                                const float* __restrict__ xorig,
                                                const float* __restrict__ dis,
                                                float* __restrict__ blend) {
    int gid = blockIdx.x * 256 + threadIdx.x; // 5000 blocks -> 20000 waves
    int wave = gid >> 6;
    int lane = gid & 63;
    int half = lane >> 5;                     // 0/1: which node this lane serves
    int l32  = lane & 31;                     // float4 slot within the row
    int node = wave * 2 + half;               // 20000*2 = 40000 exactly
    int srcb = half << 5;                     // shfl source base for own half
    const float4* x4 = (const float4*)x;

    float dc = dis[node];
    float4 sv = x4[(size_t)node * 32 + l32];
    float4 acc0 = {sv.x * dc, sv.y * dc, sv.z * dc, sv.w * dc};
    float4 acc1 = {0, 0, 0, 0}, acc2 = {0, 0, 0, 0}, acc3 = {0, 0, 0, 0};

    int p = off[node], eend = off[node + 1];
    while (__any(p < eend)) {                 // wave-uniform loop
        int ee = p + l32;
        bool act = ee < eend;
        int2 rv = act ? srn[ee] : make_int2(0, 0);
        float dl = act ? dis[rv.x] : 0.0f;
        float nm = __int_as_float(rv.y) * dl; // ew * dis[row]
        int nb = eend - p;
        nb = nb < 0 ? 0 : (nb > 32 ? 32 : nb);
        int j = 0;
        for (; j + 4 <= nb; j += 4) {
            int r0 = __shfl(rv.x, srcb + j);
            int r1 = __shfl(rv.x, srcb + j + 1);
            int r2 = __shfl(rv.x, srcb + j + 2);
            int r3 = __shfl(rv.x, srcb + j + 3);
            float n0 = __shfl(nm, srcb + j);
            float n1 = __shfl(nm, srcb + j + 1);
            float n2 = __shfl(nm, srcb + j + 2);
            float n3 = __shfl(nm, srcb + j + 3);
            float4 v0 = x4[(size_t)r0 * 32 + l32];
            float4 v1 = x4[(size_t)r1 * 32 + l32];
            float4 v2 = x4[(size_t)r2 * 32 + l32];
            float4 v3 = x4[(size_t)r3 * 32 + l32];
            acc0.x = fmaf(n0, v0.x, acc0.x); acc0.y = fmaf(n0, v0.y, acc0.y);
            acc0.z = fmaf(n0, v0.z, acc0.z); acc0.w = fmaf(n0, v0.w, acc0.w);
            acc1.x = fmaf(n1, v1.x, acc1.x); acc1.y = fmaf(n1, v1.y, acc1.y);
            acc1.z = fmaf(n1, v1.z, acc1.z); acc1.w = fmaf(n1, v1.w, acc1.w);
            acc2.x = fmaf(n2, v2.x, acc2.x); acc2.y = fmaf(n2, v2.y, acc2.y);
            acc2.z = fmaf(n2, v2.z, acc2.z); acc2.w = fmaf(n2, v2.w, acc2.w);
            acc3.x = fmaf(n3, v3.x, acc3.x); acc3.y = fmaf(n3, v3.y, acc3.y);
            acc3.z = fmaf(n3, v3.z, acc3.z); acc3.w = fmaf(n3, v3.w, acc3.w);
        }
        for (; j < nb; ++j) {
            int rr = __shfl(rv.x, srcb + j);
            float nn = __shfl(nm, srcb + j);
            float4 v = x4[(size_t)rr * 32 + l32];
            acc0.x = fmaf(nn, v.x, acc0.x); acc0.y = fmaf(nn, v.y, acc0.y);
            acc0.z = fmaf(nn, v.z, acc0.z); acc0.w = fmaf(nn, v.w, acc0.w);
        }
        p += 32;
    }
    float4 xo = ((const float4*)xorig)[(size_t)node * 32 + l32];
    float4 bl;
    bl.x = 0.9f * (dc * (acc0.x + acc1.x + acc2.x + acc3.x)) + 0.1f * xo.x;
    bl.y = 0.9f * (dc * (acc0.y + acc1.y + acc2.y + acc3.y)) + 0.1f * xo.y;
    bl.z = 0.9f * (dc * (acc0.z + acc1.z + acc2.z + acc3.z)) + 0.1f * xo.z;
    bl.w = 0.9f * (dc * (acc0.w + acc1.w + acc2.w + acc3.w)) + 0.1f * xo.w;
    ((float4*)blend)[(size_t)node * 32 + l32] = bl;
}

// ---------------- h = relu(blend @ W), 4 rows/thread ----------------
// W half-tile [128][64] = 32 KB LDS. 626 blocks, XCD-pairing swizzle:
// the two col-halves of row-block r get linear ids r and r+8 (same id%8
// -> same XCD -> second reader L2-hits the 64KB row slice).
__global__ __launch_bounds__(256) void k_matmul(const float* __restrict__ blend,
                                                const float* __restrict__ W,
                                                float* __restrict__ out) {
    int id = blockIdx.x;                      // 0..625
    int rowblk, colhalf;
    if (id >= 624) { rowblk = 312; colhalf = id - 624; }
    else { rowblk = ((id >> 4) << 3) | (id & 7); colhalf = (id >> 3) & 1; }

    __shared__ float Wl[DD * 64];             // [k][c] 32 KB
    int t = threadIdx.x;
    int jb = colhalf << 6;                    // col-half base (0 or 64)
    {   // stage W[:, jb:jb+64]: 2048 float4, 8 per thread
#pragma unroll
        for (int i = 0; i < 8; ++i) {
            int idx = i * 256 + t;
            int k = idx >> 4, jq = idx & 15;
            *(float4*)&Wl[k * 64 + jq * 4] =
                *(const float4*)&W[(size_t)k * DD + jb + jq * 4];
        }
    }
    __syncthreads();

    int rg = t >> 3;                          // 32 row-groups of 4 rows
    int cg = t & 7;                           // 8 col-groups of 8 cols
    int row0 = rowblk * 128 + rg * 4;         // 313*128 = 40064 (tail guarded)
    bool valid = (row0 + 3) < NN;
    size_t rr = valid ? (size_t)row0 : 0;
    int jc = cg * 8;

    float acc[4][8] = {};
    const float* ap = blend + rr * DD;

    for (int k0 = 0; k0 < DD; k0 += 4) {
        float in[4][4];
#pragma unroll
        for (int r = 0; r < 4; ++r) {
            float4 av = *(const float4*)(ap + r * DD + k0);
            in[r][0] = av.x; in[r][1] = av.y; in[r][2] = av.z; in[r][3] = av.w;
        }
#pragma unroll
        for (int kk = 0; kk < 4; ++kk) {
            float4 w0 = *(const float4*)&Wl[(k0 + kk) * 64 + jc];
            float4 w1 = *(const float4*)&Wl[(k0 + kk) * 64 + jc + 4];
#pragma unroll
            for (int r = 0; r < 4; ++r) {
                float a = in[r][kk];
                acc[r][0] = fmaf(a, w0.x, acc[r][0]);
                acc[r][1] = fmaf(a, w0.y, acc[r][1]);
                acc[r][2] = fmaf(a, w0.z, acc[r][2]);
                acc[r][3] = fmaf(a, w0.w, acc[r][3]);
                acc[r][4] = fmaf(a, w1.x, acc[r][4]);
                acc[r][5] = fmaf(a, w1.y, acc[r][5]);
                acc[r][6] = fmaf(a, w1.z, acc[r][6]);
                acc[r][7] = fmaf(a, w1.w, acc[r][7]);
            }
        }
    }
    if (valid) {
#pragma unroll
        for (int r = 0; r < 4; ++r) {
            float* orow = out + (rr + r) * DD + jb + jc;
            float4 v0 = {fmaxf(acc[r][0], 0.0f), fmaxf(acc[r][1], 0.0f),
                         fmaxf(acc[r][2], 0.0f), fmaxf(acc[r][3], 0.0f)};
            float4 v1 = {fmaxf(acc[r][4], 0.0f), fmaxf(acc[r][5], 0.0f),
                         fmaxf(acc[r][6], 0.0f), fmaxf(acc[r][7], 0.0f)};
            *(float4*)(orow) = v0;
            *(float4*)(orow + 4) = v1;
        }
    }
}

// ---------------- BN stats: per-column sum & sumsq ----------------
__global__ __launch_bounds__(256) void k_stats(const float* __restrict__ h,
                                               float* __restrict__ sums) {
    int t = threadIdx.x;
    int tid = blockIdx.x * 256 + t;           // 256 blocks
    int cg = t & 31;                          // float4 column group
    int row0 = tid >> 5;                      // 0..2047
    float4 s = {0, 0, 0, 0}, q = {0, 0, 0, 0};
    for (int r = row0; r < NN; r += 2048) {
        float4 v = *(const float4*)&h[(size_t)r * DD + cg * 4];
        s.x += v.x; s.y += v.y; s.z += v.z; s.w += v.w;
        q.x += v.x * v.x; q.y += v.y * v.y; q.z += v.z * v.z; q.w += v.w * v.w;
    }
    __shared__ float red[256][8];
    red[t][0] = s.x; red[t][1] = s.y; red[t][2] = s.z; red[t][3] = s.w;
    red[t][4] = q.x; red[t][5] = q.y; red[t][6] = q.z; red[t][7] = q.w;
    __syncthreads();
    if (t < 32) {
#pragma unroll
        for (int s8 = 1; s8 < 8; ++s8)
#pragma unroll
            for (int c = 0; c < 8; ++c) red[t][c] += red[t + 32 * s8][c];
        int j = t * 4;
        unsafeAtomicAdd(&sums[j + 0], red[t][0]);
        unsafeAtomicAdd(&sums[j + 1], red[t][1]);
        unsafeAtomicAdd(&sums[j + 2], red[t][2]);
        unsafeAtomicAdd(&sums[j + 3], red[t][3]);
        unsafeAtomicAdd(&sums[DD + j + 0], red[t][4]);
        unsafeAtomicAdd(&sums[DD + j + 1], red[t][5]);
        unsafeAtomicAdd(&sums[DD + j + 2], red[t][6]);
        unsafeAtomicAdd(&sums[DD + j + 3], red[t][7]);
    }
}

// ---------------- BN apply (in place on d_out) ----------------
__global__ __launch_bounds__(256) void k_apply(float* __restrict__ h,
                                               const float* __restrict__ sums,
                                               const float* __restrict__ gamma,
                                               const float* __restrict__ beta) {
    int g = blockIdx.x * 256 + threadIdx.x;   // N*32 threads
    int i = g >> 5, q = g & 31;
    int j = q * 4;
    const float invN = 1.0f / (float)NN;
    float4 sm = *(const float4*)&sums[j];
    float4 sq = *(const float4*)&sums[DD + j];
    float4 gm = *(const float4*)&gamma[j];
    float4 bt = *(const float4*)&beta[j];
    float4 v = *(float4*)&h[(size_t)i * DD + j];
    float m0 = sm.x * invN, m1 = sm.y * invN, m2 = sm.z * invN, m3 = sm.w * invN;
    float i0 = rsqrtf(fmaxf(sq.x * invN - m0 * m0, 0.0f) + 1e-5f);
    float i1 = rsqrtf(fmaxf(sq.y * invN - m1 * m1, 0.0f) + 1e-5f);
    float i2 = rsqrtf(fmaxf(sq.z * invN - m2 * m2, 0.0f) + 1e-5f);
    float i3 = rsqrtf(fmaxf(sq.w * invN - m3 * m3, 0.0f) + 1e-5f);
    v.x = (v.x - m0) * i0 * gm.x + bt.x;
    v.y = (v.y - m1) * i1 * gm.y + bt.y;
    v.z = (v.z - m2) * i2 * gm.z + bt.z;
    v.w = (v.w - m3) * i3 * gm.w + bt.w;
    *(float4*)&h[(size_t)i * DD + j] = v;
}

extern "C" void kernel_launch(void* const* d_in, const int* in_sizes, int n_in,
                              void* d_out, int out_size, void* d_ws, size_t ws_size,
                              hipStream_t stream) {
    const float* x     = (const float*)d_in[0];
    const float* xorig = (const float*)d_in[1];
    const int*   ei    = (const int*)d_in[2];
    const float* ew    = (const float*)d_in[3];
    const float* W     = (const float*)d_in[4];
    const float* gamma = (const float*)d_in[5];
    const float* beta  = (const float*)d_in[6];
    float* out = (float*)d_out;

    // workspace layout (blend first keeps 16B alignment for float4 & srn)
    float* ws    = (float*)d_ws;
    float* blend = ws;                              // N*D floats
    int2*  srn   = (int2*)(blend + (size_t)NN * DD);// E int2 (row, ew-bits)
    float* dis   = (float*)(srn + EE);              // N floats
    float* sums  = dis + NN;                        // 256 floats
    int*   cnt   = (int*)(sums + 256);              // N
    int*   off   = cnt + NN;                        // N+1
    int*   rank  = off + NN + 1;                    // E

    k_init   <<<160,   256, 0, stream>>>(cnt, sums);
    k_rank   <<<2500,  256, 0, stream>>>(ei, cnt, rank);
    k_scan   <<<1,    1024, 0, stream>>>(cnt, off);
    k_permute<<<2500,  256, 0, stream>>>(ei, ew, rank, off, srn);
    k_degdis <<<10000, 256, 0, stream>>>(off, srn, dis);
    k_gather <<<5000,  256, 0, stream>>>(off, srn, x, xorig, dis, blend);
    k_matmul <<<626,   256, 0, stream>>>(blend, W, out);
    k_stats  <<<256,   256, 0, stream>>>(out, sums);
    k_apply  <<<5000,  256, 0, stream>>>(out, sums, gamma, beta);
}

// Round 15
// 230.216 us; speedup vs baseline: 1.4486x; 1.1204x over previous
//
#include <hip/hip_runtime.h>

#define NN 40000
#define DD 128
#define EE 640000

// ---------------- init: cnt = 0, zero BN sums ----------------
__global__ __launch_bounds__(256) void k_init(int* __restrict__ cnt,
                                              float* __restrict__ sums) {
    int i = blockIdx.x * 256 + threadIdx.x;
    if (i < NN) cnt[i] = 0;
    if (i < 256) sums[i] = 0.0f;   // 128 sum + 128 sumsq
}

// ---------------- rank[e] = cnt[col]++  (the ONLY atomic pass) ----------------
__global__ __launch_bounds__(256) void k_rank(const int* __restrict__ ei,
                                              int* __restrict__ cnt,
                                              int* __restrict__ rank) {
    int e = blockIdx.x * 256 + threadIdx.x;   // E = 2500*256 exactly
    int c = ei[EE + e];
    rank[e] = atomicAdd(&cnt[c], 1);
}

// ---------------- exclusive scan of cnt -> off (single block) ----------------
#define SCAN_CH 40
__global__ __launch_bounds__(1024) void k_scan(const int* __restrict__ cnt,
                                               int* __restrict__ off) {
    __shared__ int sm[1024];
    int t = threadIdx.x;
    int base = t * SCAN_CH;                   // 1000 threads cover 40000 exactly
    int s = 0;
    if (base < NN) {
#pragma unroll
        for (int i = 0; i < SCAN_CH; ++i) s += cnt[base + i];
    }
    sm[t] = s;
    __syncthreads();
    for (int d = 1; d < 1024; d <<= 1) {      // Hillis-Steele inclusive scan
        int v = (t >= d) ? sm[t - d] : 0;
        __syncthreads();
        sm[t] += v;
        __syncthreads();
    }
    if (base < NN) {
        int run = sm[t] - s;                  // exclusive base for this chunk
#pragma unroll
        for (int i = 0; i < SCAN_CH; ++i) {
            off[base + i] = run;
            run += cnt[base + i];
        }
    }
    if (t == 1023) off[NN] = sm[1023];        // == EE
}

// ---------------- permute edges into dest-sorted order (NO atomics) ----------------
__global__ __launch_bounds__(256) void k_permute(const int* __restrict__ ei,
                                                 const float* __restrict__ ew,
                                                 const int* __restrict__ rank,
                                                 const int* __restrict__ off,
                                                 int2* __restrict__ srn) {
    int e = blockIdx.x * 256 + threadIdx.x;   // 2500 blocks
    int r = ei[e], c = ei[EE + e];
    int pos = off[c] + rank[e];
    srn[pos] = make_int2(r, __float_as_int(ew[e]));
}

// ---------------- deg from CSR segments: dis = rsqrt(1 + sum ew), wave/node ----------------
__global__ __launch_bounds__(256) void k_degdis(const int* __restrict__ off,
                                                const int2* __restrict__ srn,
                                                float* __restrict__ dis) {
    int gid = blockIdx.x * 256 + threadIdx.x; // 10000 blocks -> 40000 waves
    int node = gid >> 6;
    int lane = gid & 63;
    int s = off[node], e = off[node + 1];
    float v = 0.0f;
    for (int p = s + lane; p < e; p += 64) v += __int_as_float(srn[p].y);
#pragma unroll
    for (int m = 1; m < 64; m <<= 1) v += __shfl_xor(v, m);
    if (lane == 0) dis[node] = rsqrtf(1.0f + v);
}

// ---------------- gather: TWO nodes per wave, 8-deep load pipeline ----------------
// blend[node] = 0.9 * dc*(dc*x_c + sum nm*x_r) + 0.1 * xorig[node]
__global__ __launch_bounds__(256) void k_gather(const int* __restrict__ off,
                                                const int2* __restrict__ srn,
                                                const float* __restrict__ x,
                                                const float* __restrict__ xorig,
                                                const float* __restrict__ dis,
                                                float* __restrict__ blend) {
    int gid = blockIdx.x * 256 + threadIdx.x; // 5000 blocks -> 20000 waves
    int wave = gid >> 6;
    int lane = gid & 63;
    int half = lane >> 5;                     // 0/1: which node this lane serves
    int l32  = lane & 31;                     // float4 slot within the row
    int node = wave * 2 + half;               // 20000*2 = 40000 exactly
    int srcb = half << 5;                     // shfl source base for own half
    const float4* x4 = (const float4*)x;

    float dc = dis[node];
    float4 sv = x4[(size_t)node * 32 + l32];
    float4 a0 = {sv.x * dc, sv.y * dc, sv.z * dc, sv.w * dc};
    float4 a1 = {0, 0, 0, 0}, a2 = {0, 0, 0, 0}, a3 = {0, 0, 0, 0};

    int p = off[node], eend = off[node + 1];
    while (__any(p < eend)) {                 // wave-uniform loop
        int ee = p + l32;
        bool act = ee < eend;
        int2 rv = act ? srn[ee] : make_int2(0, 0);
        float dl = act ? dis[rv.x] : 0.0f;
        float nm = __int_as_float(rv.y) * dl; // ew * dis[row]
        int nb = eend - p;
        nb = nb < 0 ? 0 : (nb > 32 ? 32 : nb);
        int j = 0;
        for (; j + 8 <= nb; j += 8) {         // 8 independent loads in flight
            int r[8]; float n[8];
#pragma unroll
            for (int u = 0; u < 8; ++u) {
                r[u] = __shfl(rv.x, srcb + j + u);
                n[u] = __shfl(nm, srcb + j + u);
            }
            float4 v[8];
#pragma unroll
            for (int u = 0; u < 8; ++u) v[u] = x4[(size_t)r[u] * 32 + l32];
#pragma unroll
            for (int u = 0; u < 8; ++u) {
                float4* ac = (u & 3) == 0 ? &a0 : (u & 3) == 1 ? &a1
                           : (u & 3) == 2 ? &a2 : &a3;
                ac->x = fmaf(n[u], v[u].x, ac->x);
                ac->y = fmaf(n[u], v[u].y, ac->y);
                ac->z = fmaf(n[u], v[u].z, ac->z);
                ac->w = fmaf(n[u], v[u].w, ac->w);
            }
        }
        for (; j < nb; ++j) {
            int rr = __shfl(rv.x, srcb + j);
            float nn = __shfl(nm, srcb + j);
            float4 v = x4[(size_t)rr * 32 + l32];
            a0.x = fmaf(nn, v.x, a0.x); a0.y = fmaf(nn, v.y, a0.y);
            a0.z = fmaf(nn, v.z, a0.z); a0.w = fmaf(nn, v.w, a0.w);
        }
        p += 32;
    }
    float4 xo = ((const float4*)xorig)[(size_t)node * 32 + l32];
    float4 bl;
    bl.x = 0.9f * (dc * (a0.x + a1.x + a2.x + a3.x)) + 0.1f * xo.x;
    bl.y = 0.9f * (dc * (a0.y + a1.y + a2.y + a3.y)) + 0.1f * xo.y;
    bl.z = 0.9f * (dc * (a0.z + a1.z + a2.z + a3.z)) + 0.1f * xo.z;
    bl.w = 0.9f * (dc * (a0.w + a1.w + a2.w + a3.w)) + 0.1f * xo.w;
    ((float4*)blend)[(size_t)node * 32 + l32] = bl;
}

// ---------------- h = relu(blend @ W) + fused BN partial stats ----------------
// W half-tile [128][64] = 32 KB LDS + 16 KB reduce = 48 KB (3 blocks/CU).
// 626 blocks, XCD-pairing swizzle: col-halves of row-block r get ids r, r+8.
__global__ __launch_bounds__(256) void k_matmul(const float* __restrict__ blend,
                                                const float* __restrict__ W,
                                                float* __restrict__ out,
                                                float* __restrict__ sums) {
    int id = blockIdx.x;                      // 0..625
    int rowblk, colhalf;
    if (id >= 624) { rowblk = 312; colhalf = id - 624; }
    else { rowblk = ((id >> 4) << 3) | (id & 7); colhalf = (id >> 3) & 1; }

    __shared__ float Wl[DD * 64];             // [k][c] 32 KB
    __shared__ float red[256][16];            // 16 KB stats reduce
    int t = threadIdx.x;
    int jb = colhalf << 6;                    // col-half base (0 or 64)
    {   // stage W[:, jb:jb+64]: 2048 float4, 8 per thread
#pragma unroll
        for (int i = 0; i < 8; ++i) {
            int idx = i * 256 + t;
            int k = idx >> 4, jq = idx & 15;
            *(float4*)&Wl[k * 64 + jq * 4] =
                *(const float4*)&W[(size_t)k * DD + jb + jq * 4];
        }
    }
    __syncthreads();

    int rg = t >> 3;                          // 32 row-groups of 4 rows
    int cg = t & 7;                           // 8 col-groups of 8 cols
    int row0 = rowblk * 128 + rg * 4;         // 313*128 = 40064 (tail guarded)
    bool valid = (row0 + 3) < NN;
    size_t rr = valid ? (size_t)row0 : 0;
    int jc = cg * 8;

    float acc[4][8] = {};
    const float* ap = blend + rr * DD;

    for (int k0 = 0; k0 < DD; k0 += 4) {
        float in[4][4];
#pragma unroll
        for (int r = 0; r < 4; ++r) {
            float4 av = *(const float4*)(ap + r * DD + k0);
            in[r][0] = av.x; in[r][1] = av.y; in[r][2] = av.z; in[r][3] = av.w;
        }
#pragma unroll
        for (int kk = 0; kk < 4; ++kk) {
            float4 w0 = *(const float4*)&Wl[(k0 + kk) * 64 + jc];
            float4 w1 = *(const float4*)&Wl[(k0 + kk) * 64 + jc + 4];
#pragma unroll
            for (int r = 0; r < 4; ++r) {
                float a = in[r][kk];
                acc[r][0] = fmaf(a, w0.x, acc[r][0]);
                acc[r][1] = fmaf(a, w0.y, acc[r][1]);
                acc[r][2] = fmaf(a, w0.z, acc[r][2]);
                acc[r][3] = fmaf(a, w0.w, acc[r][3]);
                acc[r][4] = fmaf(a, w1.x, acc[r][4]);
                acc[r][5] = fmaf(a, w1.y, acc[r][5]);
                acc[r][6] = fmaf(a, w1.z, acc[r][6]);
                acc[r][7] = fmaf(a, w1.w, acc[r][7]);
            }
        }
    }
    // relu in place, write out, accumulate local BN stats
    float ls[8] = {}, lq[8] = {};
    if (valid) {
#pragma unroll
        for (int r = 0; r < 4; ++r) {
#pragma unroll
            for (int c = 0; c < 8; ++c) {
                float v = fmaxf(acc[r][c], 0.0f);
                acc[r][c] = v;
                ls[c] += v;
                lq[c] += v * v;
            }
            float* orow = out + (rr + r) * DD + jb + jc;
            *(float4*)(orow)     = *(float4*)&acc[r][0];
            *(float4*)(orow + 4) = *(float4*)&acc[r][4];
        }
    }
#pragma unroll
    for (int c = 0; c < 8; ++c) { red[t][c] = ls[c]; red[t][8 + c] = lq[c]; }
    __syncthreads();
    if (t < 64) {                             // one thread per column of the half
        int cg2 = t >> 3, c2 = t & 7;
        float s = 0.f, q = 0.f;
#pragma unroll
        for (int rg2 = 0; rg2 < 32; ++rg2) {
            s += red[rg2 * 8 + cg2][c2];
            q += red[rg2 * 8 + cg2][8 + c2];
        }
        unsafeAtomicAdd(&sums[jb + cg2 * 8 + c2], s);
        unsafeAtomicAdd(&sums[DD + jb + cg2 * 8 + c2], q);
    }
}

// ---------------- BN apply (in place on d_out) ----------------
__global__ __launch_bounds__(256) void k_apply(float* __restrict__ h,
                                               const float* __restrict__ sums,
                                               const float* __restrict__ gamma,
                                               const float* __restrict__ beta) {
    int g = blockIdx.x * 256 + threadIdx.x;   // N*32 threads
    int i = g >> 5, q = g & 31;
    int j = q * 4;
    const float invN = 1.0f / (float)NN;
    float4 sm = *(const float4*)&sums[j];
    float4 sq = *(const float4*)&sums[DD + j];
    float4 gm = *(const float4*)&gamma[j];
    float4 bt = *(const float4*)&beta[j];
    float4 v = *(float4*)&h[(size_t)i * DD + j];
    float m0 = sm.x * invN, m1 = sm.y * invN, m2 = sm.z * invN, m3 = sm.w * invN;
    float i0 = rsqrtf(fmaxf(sq.x * invN - m0 * m0, 0.0f) + 1e-5f);
    float i1 = rsqrtf(fmaxf(sq.y * invN - m1 * m1, 0.0f) + 1e-5f);
    float i2 = rsqrtf(fmaxf(sq.z * invN - m2 * m2, 0.0f) + 1e-5f);
    float i3 = rsqrtf(fmaxf(sq.w * invN - m3 * m3, 0.0f) + 1e-5f);
    v.x = (v.x - m0) * i0 * gm.x + bt.x;
    v.y = (v.y - m1) * i1 * gm.y + bt.y;
    v.z = (v.z - m2) * i2 * gm.z + bt.z;
    v.w = (v.w - m3) * i3 * gm.w + bt.w;
    *(float4*)&h[(size_t)i * DD + j] = v;
}

extern "C" void kernel_launch(void* const* d_in, const int* in_sizes, int n_in,
                              void* d_out, int out_size, void* d_ws, size_t ws_size,
                              hipStream_t stream) {
    const float* x     = (const float*)d_in[0];
    const float* xorig = (const float*)d_in[1];
    const int*   ei    = (const int*)d_in[2];
    const float* ew    = (const float*)d_in[3];
    const float* W     = (const float*)d_in[4];
    const float* gamma = (const float*)d_in[5];
    const float* beta  = (const float*)d_in[6];
    float* out = (float*)d_out;

    // workspace layout (blend first keeps 16B alignment for float4 & srn)
    float* ws    = (float*)d_ws;
    float* blend = ws;                              // N*D floats
    int2*  srn   = (int2*)(blend + (size_t)NN * DD);// E int2 (row, ew-bits)
    float* dis   = (float*)(srn + EE);              // N floats
    float* sums  = dis + NN;                        // 256 floats
    int*   cnt   = (int*)(sums + 256);              // N
    int*   off   = cnt + NN;                        // N+1
    int*   rank  = off + NN + 1;                    // E

    k_init   <<<160,   256, 0, stream>>>(cnt, sums);
    k_rank   <<<2500,  256, 0, stream>>>(ei, cnt, rank);
    k_scan   <<<1,    1024, 0, stream>>>(cnt, off);
    k_permute<<<2500,  256, 0, stream>>>(ei, ew, rank, off, srn);
    k_degdis <<<10000, 256, 0, stream>>>(off, srn, dis);
    k_gather <<<5000,  256, 0, stream>>>(off, srn, x, xorig, dis, blend);
    k_matmul <<<626,   256, 0, stream>>>(blend, W, out, sums);
    k_apply  <<<5000,  256, 0, stream>>>(out, sums, gamma, beta);
}